// Round 2
// baseline (2200.814 us; speedup 1.0000x reference)
//
#include <hip/hip_runtime.h>

#define NN 100000
#define NE 1250000
#define DD 64

// ---------------- precompute: Wc1 = W2 @ Wl[64:128], Wc2 = W2 @ Wl[128:192],
// ----------------             bc = b_lin + b2 @ (Wl[64:128] + Wl[128:192])
__global__ __launch_bounds__(256) void precompute_kernel(
    const float* __restrict__ W2, const float* __restrict__ b2,
    const float* __restrict__ Wl, const float* __restrict__ bl,
    float* __restrict__ Wc1, float* __restrict__ Wc2, float* __restrict__ bc) {
  const int t = blockIdx.x * 256 + threadIdx.x;   // 32 blocks x 256 = 8192
  const int m = t >> 12;                           // 0 -> Wc1, 1 -> Wc2
  const int ij = t & 4095;
  const int i = ij >> 6, j = ij & 63;
  const float* Wp = Wl + (m ? 128 : 64) * 64;
  float s = 0.f;
#pragma unroll 8
  for (int k = 0; k < 64; ++k) s = fmaf(W2[i * 64 + k], Wp[k * 64 + j], s);
  if (m) Wc2[ij] = s; else Wc1[ij] = s;
  if (t < 64) {
    float sb = bl[t];
    for (int k = 0; k < 64; ++k)
      sb = fmaf(b2[k], Wl[(64 + k) * 64 + t] + Wl[(128 + k) * 64 + t], sb);
    bc[t] = sb;
  }
}

// ---------------- edge pass: one read of edge_attr, both directions scattered
// 16 lanes per edge, float4 per lane.
__global__ __launch_bounds__(256) void edge_kernel(
    const float* __restrict__ x, const int* __restrict__ ei,
    const float* __restrict__ ea,
    float* __restrict__ agg_in, float* __restrict__ agg_out) {
  const int tid = blockIdx.x * 256 + threadIdx.x;
  const int e = tid >> 4;
  if (e >= NE) return;
  const int c = (tid & 15) * 4;
  const int s = ei[e];
  const int d = ei[NE + e];
  const float4 a  = *reinterpret_cast<const float4*>(ea + (size_t)e * DD + c);
  const float4 xs = *reinterpret_cast<const float4*>(x + (size_t)s * DD + c);
  const float4 xd = *reinterpret_cast<const float4*>(x + (size_t)d * DD + c);
  float* pi = agg_in + (size_t)d * DD + c;
  unsafeAtomicAdd(pi + 0, fmaxf(xs.x + a.x, 0.f));
  unsafeAtomicAdd(pi + 1, fmaxf(xs.y + a.y, 0.f));
  unsafeAtomicAdd(pi + 2, fmaxf(xs.z + a.z, 0.f));
  unsafeAtomicAdd(pi + 3, fmaxf(xs.w + a.w, 0.f));
  float* po = agg_out + (size_t)s * DD + c;
  unsafeAtomicAdd(po + 0, fmaxf(xd.x + a.x, 0.f));
  unsafeAtomicAdd(po + 1, fmaxf(xd.y + a.y, 0.f));
  unsafeAtomicAdd(po + 2, fmaxf(xd.z + a.z, 0.f));
  unsafeAtomicAdd(po + 3, fmaxf(xd.w + a.w, 0.f));
}

// ---------------- fused node MLP + final projection ----------------
// 64-node tile per block, 256 threads. LDS tiles stored TRANSPOSED [k][n],
// row stride 66 floats. Thread (jq = t&15, nq = t>>4) owns 4n x 4j outputs.
// Passes: h1=relu(Ain@W1+b1); o+=h1@Wc1; h2=relu(Aout@W1+b1); o+=h2@Wc2;
//         o+=x@Wl0 + bc.

#define LDSTRIDE 66

#define LOAD_TILE(SRC, Bbuf)                                                  \
  {                                                                           \
    const int r = t >> 2;                                                     \
    const int cb = (t & 3) * 16;                                              \
    const int n = n0 + r;                                                     \
    _Pragma("unroll") for (int ii = 0; ii < 4; ++ii) {                        \
      float4 v = make_float4(0.f, 0.f, 0.f, 0.f);                             \
      if (n < NN)                                                             \
        v = *reinterpret_cast<const float4*>((SRC) + (size_t)n * DD + cb +    \
                                             ii * 4);                         \
      const int cc = cb + ii * 4;                                             \
      Bbuf[(cc + 0) * LDSTRIDE + r] = v.x;                                    \
      Bbuf[(cc + 1) * LDSTRIDE + r] = v.y;                                    \
      Bbuf[(cc + 2) * LDSTRIDE + r] = v.z;                                    \
      Bbuf[(cc + 3) * LDSTRIDE + r] = v.w;                                    \
    }                                                                         \
  }

#define MM_PASS(Bbuf, Wmat, ACC)                                              \
  {                                                                           \
    _Pragma("unroll 8") for (int k = 0; k < 64; ++k) {                        \
      const float4 w =                                                        \
          *reinterpret_cast<const float4*>((Wmat) + k * 64 + jq * 4);         \
      _Pragma("unroll") for (int ii = 0; ii < 4; ++ii) {                      \
        const float aa = Bbuf[k * LDSTRIDE + nq * 4 + ii];                    \
        ACC[ii][0] = fmaf(aa, w.x, ACC[ii][0]);                               \
        ACC[ii][1] = fmaf(aa, w.y, ACC[ii][1]);                               \
        ACC[ii][2] = fmaf(aa, w.z, ACC[ii][2]);                               \
        ACC[ii][3] = fmaf(aa, w.w, ACC[ii][3]);                               \
      }                                                                       \
    }                                                                         \
  }

// store h = relu(acc + b1[j]) transposed into Bbuf[j][n]
#define STORE_H(Bbuf, ACC, BV)                                                \
  {                                                                           \
    _Pragma("unroll") for (int ii = 0; ii < 4; ++ii) {                        \
      Bbuf[(jq * 4 + 0) * LDSTRIDE + nq * 4 + ii] =                           \
          fmaxf(ACC[ii][0] + BV.x, 0.f);                                      \
      Bbuf[(jq * 4 + 1) * LDSTRIDE + nq * 4 + ii] =                           \
          fmaxf(ACC[ii][1] + BV.y, 0.f);                                      \
      Bbuf[(jq * 4 + 2) * LDSTRIDE + nq * 4 + ii] =                           \
          fmaxf(ACC[ii][2] + BV.z, 0.f);                                      \
      Bbuf[(jq * 4 + 3) * LDSTRIDE + nq * 4 + ii] =                           \
          fmaxf(ACC[ii][3] + BV.w, 0.f);                                      \
    }                                                                         \
  }

__global__ __launch_bounds__(256) void node_kernel(
    const float* __restrict__ x, const float* __restrict__ agg_in,
    const float* __restrict__ agg_out, const float* __restrict__ W1,
    const float* __restrict__ b1, const float* __restrict__ Wc1,
    const float* __restrict__ Wc2, const float* __restrict__ bc,
    const float* __restrict__ Wl0, float* __restrict__ out) {
  __shared__ float B0[64 * LDSTRIDE];
  __shared__ float B1[64 * LDSTRIDE];
  const int t = threadIdx.x;
  const int n0 = blockIdx.x * 64;
  const int jq = t & 15;
  const int nq = t >> 4;

  const float4 b1v = *reinterpret_cast<const float4*>(b1 + jq * 4);
  const float4 bcv = *reinterpret_cast<const float4*>(bc + jq * 4);

  float oacc[4][4];
#pragma unroll
  for (int ii = 0; ii < 4; ++ii)
#pragma unroll
    for (int jj = 0; jj < 4; ++jj) oacc[ii][jj] = 0.f;

  // ---- forward conv hidden layer
  LOAD_TILE(agg_in, B0);
  __syncthreads();
  {
    float acc[4][4] = {};
    MM_PASS(B0, W1, acc);
    STORE_H(B1, acc, b1v);
  }
  __syncthreads();  // B1 ready; B0 free
  MM_PASS(B1, Wc1, oacc);
  LOAD_TILE(agg_out, B0);
  __syncthreads();  // B0 ready; everyone done reading B1
  {
    float acc[4][4] = {};
    MM_PASS(B0, W1, acc);
    STORE_H(B1, acc, b1v);
  }
  __syncthreads();  // B1 ready; B0 free
  MM_PASS(B1, Wc2, oacc);
  LOAD_TILE(x, B0);
  __syncthreads();  // B0 (x tile) ready
  MM_PASS(B0, Wl0, oacc);

  // ---- store out[n][j] = oacc + bc[j]
#pragma unroll
  for (int ii = 0; ii < 4; ++ii) {
    const int n = n0 + nq * 4 + ii;
    if (n < NN) {
      float4 v;
      v.x = oacc[ii][0] + bcv.x;
      v.y = oacc[ii][1] + bcv.y;
      v.z = oacc[ii][2] + bcv.z;
      v.w = oacc[ii][3] + bcv.w;
      *reinterpret_cast<float4*>(out + (size_t)n * DD + jq * 4) = v;
    }
  }
}

extern "C" void kernel_launch(void* const* d_in, const int* in_sizes, int n_in,
                              void* d_out, int out_size, void* d_ws,
                              size_t ws_size, hipStream_t stream) {
  const float* x  = (const float*)d_in[0];
  const int*   ei = (const int*)d_in[1];
  const float* ea = (const float*)d_in[2];
  const float* W1 = (const float*)d_in[3];
  const float* b1 = (const float*)d_in[4];
  const float* W2 = (const float*)d_in[5];
  const float* b2 = (const float*)d_in[6];
  const float* Wl = (const float*)d_in[7];
  const float* bl = (const float*)d_in[8];
  float* out = (float*)d_out;
  float* ws = (float*)d_ws;

  float* agg_in  = ws;
  float* agg_out = ws + (size_t)NN * DD;
  float* Wc1     = ws + 2 * (size_t)NN * DD;
  float* Wc2     = Wc1 + 64 * 64;
  float* bc      = Wc2 + 64 * 64;

  hipMemsetAsync(agg_in, 0, 2 * (size_t)NN * DD * sizeof(float), stream);
  precompute_kernel<<<32, 256, 0, stream>>>(W2, b2, Wl, bl, Wc1, Wc2, bc);
  edge_kernel<<<(NE * 16 + 255) / 256, 256, 0, stream>>>(x, ei, ea, agg_in,
                                                         agg_out);
  node_kernel<<<(NN + 63) / 64, 256, 0, stream>>>(
      x, agg_in, agg_out, W1, b1, Wc1, Wc2, bc, Wl /* rows 0..63 */, out);
}

// Round 3
// 837.612 us; speedup vs baseline: 2.6275x; 2.6275x over previous
//
#include <hip/hip_runtime.h>

#define NN 100000
#define NE 1250000
#define DD 64
#define SCAN_THREADS 1024
#define SCAN_CHUNK 98  // 1024*98 = 100352 >= NN

// ---------------- precompute: Wc1 = W2 @ Wl[64:128], Wc2 = W2 @ Wl[128:192],
// ----------------             bc = b_lin + b2 @ (Wl[64:128] + Wl[128:192])
__global__ __launch_bounds__(256) void precompute_kernel(
    const float* __restrict__ W2, const float* __restrict__ b2,
    const float* __restrict__ Wl, const float* __restrict__ bl,
    float* __restrict__ Wc1, float* __restrict__ Wc2, float* __restrict__ bc) {
  const int t = blockIdx.x * 256 + threadIdx.x;  // 32 blocks x 256 = 8192
  const int m = t >> 12;                         // 0 -> Wc1, 1 -> Wc2
  const int ij = t & 4095;
  const int i = ij >> 6, j = ij & 63;
  const float* Wp = Wl + (m ? 128 : 64) * 64;
  float s = 0.f;
#pragma unroll 8
  for (int k = 0; k < 64; ++k) s = fmaf(W2[i * 64 + k], Wp[k * 64 + j], s);
  if (m) Wc2[ij] = s; else Wc1[ij] = s;
  if (t < 64) {
    float sb = bl[t];
    for (int k = 0; k < 64; ++k)
      sb = fmaf(b2[k], Wl[(64 + k) * 64 + t] + Wl[(128 + k) * 64 + t], sb);
    bc[t] = sb;
  }
}

// ---------------- CSR build: histogram -> scan -> scatter ----------------
__global__ __launch_bounds__(256) void hist_kernel(const int* __restrict__ ei,
                                                   int* __restrict__ cnt_dst,
                                                   int* __restrict__ cnt_src) {
  const int e = blockIdx.x * 256 + threadIdx.x;
  if (e >= NE) return;
  atomicAdd(&cnt_dst[ei[NE + e]], 1);
  atomicAdd(&cnt_src[ei[e]], 1);
}

// One block per array. Converts cnt[] (counts) in place into row-start
// offsets (the scatter cursor) and writes off[] = row starts, off[NN] = total.
__global__ __launch_bounds__(SCAN_THREADS) void scan_kernel(
    int* __restrict__ cnt_d, int* __restrict__ off_d,
    int* __restrict__ cnt_s, int* __restrict__ off_s) {
  int* cnt = blockIdx.x ? cnt_s : cnt_d;
  int* off = blockIdx.x ? off_s : off_d;
  __shared__ int part[SCAN_THREADS];
  const int t = threadIdx.x;
  const int lo = t * SCAN_CHUNK;
  const int hi = (lo + SCAN_CHUNK < NN) ? lo + SCAN_CHUNK : NN;
  int s = 0;
  for (int i = lo; i < hi; ++i) s += cnt[i];
  part[t] = s;
  __syncthreads();
  int v = s;
  for (int d = 1; d < SCAN_THREADS; d <<= 1) {
    const int addv = (t >= d) ? part[t - d] : 0;
    __syncthreads();
    v += addv;
    part[t] = v;
    __syncthreads();
  }
  int pre = v - s;  // exclusive prefix of this thread's chunk
  for (int i = lo; i < hi; ++i) {
    const int c = cnt[i];
    off[i] = pre;
    cnt[i] = pre;  // becomes the scatter cursor
    pre += c;
  }
  if (t == SCAN_THREADS - 1) off[NN] = pre;
}

__global__ __launch_bounds__(256) void scatter_kernel(
    const int* __restrict__ ei, int* __restrict__ cur_dst,
    int* __restrict__ cur_src, int2* __restrict__ lst_dst,
    int2* __restrict__ lst_src) {
  const int e = blockIdx.x * 256 + threadIdx.x;
  if (e >= NE) return;
  const int s = ei[e], d = ei[NE + e];
  const int p = atomicAdd(&cur_dst[d], 1);
  lst_dst[p] = make_int2(e, s);
  const int q = atomicAdd(&cur_src[s], 1);
  lst_src[q] = make_int2(e, d);
}

// ---------------- gather: agg[n] = sum_e relu(x[partner] + ea[e]) ----------
// 16 lanes per node (float4 each), 16 nodes per 256-thread block.
__global__ __launch_bounds__(256) void gather_kernel(
    const float* __restrict__ x, const float* __restrict__ ea,
    const int* __restrict__ off, const int2* __restrict__ lst,
    float* __restrict__ agg) {
  const int t = threadIdx.x;
  const int n = blockIdx.x * 16 + (t >> 4);
  const int c = (t & 15) * 4;
  if (n >= NN) return;
  const int beg = off[n];
  const int end = off[n + 1];
  float4 acc = make_float4(0.f, 0.f, 0.f, 0.f);
  for (int k = beg; k < end; ++k) {
    const int2 p = lst[k];
    const float4 a = *reinterpret_cast<const float4*>(ea + (size_t)p.x * DD + c);
    const float4 xv = *reinterpret_cast<const float4*>(x + (size_t)p.y * DD + c);
    acc.x += fmaxf(a.x + xv.x, 0.f);
    acc.y += fmaxf(a.y + xv.y, 0.f);
    acc.z += fmaxf(a.z + xv.z, 0.f);
    acc.w += fmaxf(a.w + xv.w, 0.f);
  }
  *reinterpret_cast<float4*>(agg + (size_t)n * DD + c) = acc;
}

// ---------------- fallback edge pass (atomic) if ws too small -------------
__global__ __launch_bounds__(256) void edge_kernel(
    const float* __restrict__ x, const int* __restrict__ ei,
    const float* __restrict__ ea, float* __restrict__ agg_in,
    float* __restrict__ agg_out) {
  const int tid = blockIdx.x * 256 + threadIdx.x;
  const int e = tid >> 4;
  if (e >= NE) return;
  const int c = (tid & 15) * 4;
  const int s = ei[e];
  const int d = ei[NE + e];
  const float4 a = *reinterpret_cast<const float4*>(ea + (size_t)e * DD + c);
  const float4 xs = *reinterpret_cast<const float4*>(x + (size_t)s * DD + c);
  const float4 xd = *reinterpret_cast<const float4*>(x + (size_t)d * DD + c);
  float* pi = agg_in + (size_t)d * DD + c;
  unsafeAtomicAdd(pi + 0, fmaxf(xs.x + a.x, 0.f));
  unsafeAtomicAdd(pi + 1, fmaxf(xs.y + a.y, 0.f));
  unsafeAtomicAdd(pi + 2, fmaxf(xs.z + a.z, 0.f));
  unsafeAtomicAdd(pi + 3, fmaxf(xs.w + a.w, 0.f));
  float* po = agg_out + (size_t)s * DD + c;
  unsafeAtomicAdd(po + 0, fmaxf(xd.x + a.x, 0.f));
  unsafeAtomicAdd(po + 1, fmaxf(xd.y + a.y, 0.f));
  unsafeAtomicAdd(po + 2, fmaxf(xd.z + a.z, 0.f));
  unsafeAtomicAdd(po + 3, fmaxf(xd.w + a.w, 0.f));
}

// ---------------- fused node MLP + final projection ----------------
#define LDSTRIDE 66

#define LOAD_TILE(SRC, Bbuf)                                                  \
  {                                                                           \
    const int r = t >> 2;                                                     \
    const int cb = (t & 3) * 16;                                              \
    const int n = n0 + r;                                                     \
    _Pragma("unroll") for (int ii = 0; ii < 4; ++ii) {                        \
      float4 v = make_float4(0.f, 0.f, 0.f, 0.f);                             \
      if (n < NN)                                                             \
        v = *reinterpret_cast<const float4*>((SRC) + (size_t)n * DD + cb +    \
                                             ii * 4);                         \
      const int cc = cb + ii * 4;                                             \
      Bbuf[(cc + 0) * LDSTRIDE + r] = v.x;                                    \
      Bbuf[(cc + 1) * LDSTRIDE + r] = v.y;                                    \
      Bbuf[(cc + 2) * LDSTRIDE + r] = v.z;                                    \
      Bbuf[(cc + 3) * LDSTRIDE + r] = v.w;                                    \
    }                                                                         \
  }

#define MM_PASS(Bbuf, Wmat, ACC)                                              \
  {                                                                           \
    _Pragma("unroll 8") for (int k = 0; k < 64; ++k) {                        \
      const float4 w =                                                        \
          *reinterpret_cast<const float4*>((Wmat) + k * 64 + jq * 4);         \
      _Pragma("unroll") for (int ii = 0; ii < 4; ++ii) {                      \
        const float aa = Bbuf[k * LDSTRIDE + nq * 4 + ii];                    \
        ACC[ii][0] = fmaf(aa, w.x, ACC[ii][0]);                               \
        ACC[ii][1] = fmaf(aa, w.y, ACC[ii][1]);                               \
        ACC[ii][2] = fmaf(aa, w.z, ACC[ii][2]);                               \
        ACC[ii][3] = fmaf(aa, w.w, ACC[ii][3]);                               \
      }                                                                       \
    }                                                                         \
  }

#define STORE_H(Bbuf, ACC, BV)                                                \
  {                                                                           \
    _Pragma("unroll") for (int ii = 0; ii < 4; ++ii) {                        \
      Bbuf[(jq * 4 + 0) * LDSTRIDE + nq * 4 + ii] =                           \
          fmaxf(ACC[ii][0] + BV.x, 0.f);                                      \
      Bbuf[(jq * 4 + 1) * LDSTRIDE + nq * 4 + ii] =                           \
          fmaxf(ACC[ii][1] + BV.y, 0.f);                                      \
      Bbuf[(jq * 4 + 2) * LDSTRIDE + nq * 4 + ii] =                           \
          fmaxf(ACC[ii][2] + BV.z, 0.f);                                      \
      Bbuf[(jq * 4 + 3) * LDSTRIDE + nq * 4 + ii] =                           \
          fmaxf(ACC[ii][3] + BV.w, 0.f);                                      \
    }                                                                         \
  }

__global__ __launch_bounds__(256) void node_kernel(
    const float* __restrict__ x, const float* __restrict__ agg_in,
    const float* __restrict__ agg_out, const float* __restrict__ W1,
    const float* __restrict__ b1, const float* __restrict__ Wc1,
    const float* __restrict__ Wc2, const float* __restrict__ bc,
    const float* __restrict__ Wl0, float* __restrict__ out) {
  __shared__ float B0[64 * LDSTRIDE];
  __shared__ float B1[64 * LDSTRIDE];
  const int t = threadIdx.x;
  const int n0 = blockIdx.x * 64;
  const int jq = t & 15;
  const int nq = t >> 4;

  const float4 b1v = *reinterpret_cast<const float4*>(b1 + jq * 4);
  const float4 bcv = *reinterpret_cast<const float4*>(bc + jq * 4);

  float oacc[4][4];
#pragma unroll
  for (int ii = 0; ii < 4; ++ii)
#pragma unroll
    for (int jj = 0; jj < 4; ++jj) oacc[ii][jj] = 0.f;

  LOAD_TILE(agg_in, B0);
  __syncthreads();
  {
    float acc[4][4] = {};
    MM_PASS(B0, W1, acc);
    STORE_H(B1, acc, b1v);
  }
  __syncthreads();
  MM_PASS(B1, Wc1, oacc);
  LOAD_TILE(agg_out, B0);
  __syncthreads();
  {
    float acc[4][4] = {};
    MM_PASS(B0, W1, acc);
    STORE_H(B1, acc, b1v);
  }
  __syncthreads();
  MM_PASS(B1, Wc2, oacc);
  LOAD_TILE(x, B0);
  __syncthreads();
  MM_PASS(B0, Wl0, oacc);

#pragma unroll
  for (int ii = 0; ii < 4; ++ii) {
    const int n = n0 + nq * 4 + ii;
    if (n < NN) {
      float4 v;
      v.x = oacc[ii][0] + bcv.x;
      v.y = oacc[ii][1] + bcv.y;
      v.z = oacc[ii][2] + bcv.z;
      v.w = oacc[ii][3] + bcv.w;
      *reinterpret_cast<float4*>(out + (size_t)n * DD + jq * 4) = v;
    }
  }
}

extern "C" void kernel_launch(void* const* d_in, const int* in_sizes, int n_in,
                              void* d_out, int out_size, void* d_ws,
                              size_t ws_size, hipStream_t stream) {
  const float* x = (const float*)d_in[0];
  const int* ei = (const int*)d_in[1];
  const float* ea = (const float*)d_in[2];
  const float* W1 = (const float*)d_in[3];
  const float* b1 = (const float*)d_in[4];
  const float* W2 = (const float*)d_in[5];
  const float* b2 = (const float*)d_in[6];
  const float* Wl = (const float*)d_in[7];
  const float* bl = (const float*)d_in[8];
  float* out = (float*)d_out;
  float* ws = (float*)d_ws;

  // shared layout head: agg buffers
  float* agg_in = ws;
  float* agg_out = agg_in + (size_t)NN * DD;

  // CSR-path layout
  int2* lst_dst = (int2*)(agg_out + (size_t)NN * DD);
  int2* lst_src = lst_dst + NE;
  int* cur_dst = (int*)(lst_src + NE);
  int* cur_src = cur_dst + NN;
  int* off_dst = cur_src + NN;         // NN+2 ints
  int* off_src = off_dst + NN + 2;     // NN+2 ints
  float* Wc1 = (float*)(off_src + NN + 2);
  float* Wc2 = Wc1 + 4096;
  float* bc = Wc2 + 4096;
  const size_t need =
      (size_t)((char*)(bc + 64) - (char*)ws);  // ~72.8 MB

  const bool csr_ok = ws_size >= need;
  if (!csr_ok) {
    // fallback layout (old atomic path)
    Wc1 = agg_out + (size_t)NN * DD;
    Wc2 = Wc1 + 4096;
    bc = Wc2 + 4096;
  }

  precompute_kernel<<<32, 256, 0, stream>>>(W2, b2, Wl, bl, Wc1, Wc2, bc);

  if (csr_ok) {
    hipMemsetAsync(cur_dst, 0, 2 * (size_t)NN * sizeof(int), stream);
    hist_kernel<<<(NE + 255) / 256, 256, 0, stream>>>(ei, cur_dst, cur_src);
    scan_kernel<<<2, SCAN_THREADS, 0, stream>>>(cur_dst, off_dst, cur_src,
                                                off_src);
    scatter_kernel<<<(NE + 255) / 256, 256, 0, stream>>>(ei, cur_dst, cur_src,
                                                         lst_dst, lst_src);
    gather_kernel<<<(NN + 15) / 16, 256, 0, stream>>>(x, ea, off_dst, lst_dst,
                                                      agg_in);
    gather_kernel<<<(NN + 15) / 16, 256, 0, stream>>>(x, ea, off_src, lst_src,
                                                      agg_out);
  } else {
    hipMemsetAsync(agg_in, 0, 2 * (size_t)NN * DD * sizeof(float), stream);
    edge_kernel<<<((size_t)NE * 16 + 255) / 256, 256, 0, stream>>>(
        x, ei, ea, agg_in, agg_out);
  }

  node_kernel<<<(NN + 63) / 64, 256, 0, stream>>>(
      x, agg_in, agg_out, W1, b1, Wc1, Wc2, bc, Wl /* rows 0..63 */, out);
}

// Round 4
// 617.196 us; speedup vs baseline: 3.5658x; 1.3571x over previous
//
#include <hip/hip_runtime.h>

#define NN 100000
#define NE 1250000
#define DD 64
#define NB 98  // scan blocks per array: 98 * 1024 >= NN

// ---------------- precompute: Wc1 = W2 @ Wl[64:128], Wc2 = W2 @ Wl[128:192],
// ----------------             bc = b_lin + b2 @ (Wl[64:128] + Wl[128:192])
__global__ __launch_bounds__(256) void precompute_kernel(
    const float* __restrict__ W2, const float* __restrict__ b2,
    const float* __restrict__ Wl, const float* __restrict__ bl,
    float* __restrict__ Wc1, float* __restrict__ Wc2, float* __restrict__ bc) {
  const int t = blockIdx.x * 256 + threadIdx.x;  // 32 blocks x 256 = 8192
  const int m = t >> 12;                         // 0 -> Wc1, 1 -> Wc2
  const int ij = t & 4095;
  const int i = ij >> 6, j = ij & 63;
  const float* Wp = Wl + (m ? 128 : 64) * 64;
  float s = 0.f;
#pragma unroll 8
  for (int k = 0; k < 64; ++k) s = fmaf(W2[i * 64 + k], Wp[k * 64 + j], s);
  if (m) Wc2[ij] = s; else Wc1[ij] = s;
  if (t < 64) {
    float sb = bl[t];
    for (int k = 0; k < 64; ++k)
      sb = fmaf(b2[k], Wl[(64 + k) * 64 + t] + Wl[(128 + k) * 64 + t], sb);
    bc[t] = sb;
  }
}

// ---------------- CSR build: histogram -> 3-phase scan -> scatter ---------
__global__ __launch_bounds__(256) void hist_kernel(const int* __restrict__ ei,
                                                   int* __restrict__ cnt_dst,
                                                   int* __restrict__ cnt_src) {
  const int e = blockIdx.x * 256 + threadIdx.x;
  if (e >= NE) return;
  atomicAdd(&cnt_dst[ei[NE + e]], 1);
  atomicAdd(&cnt_src[ei[e]], 1);
}

// phase 1: per-block sums. gridDim = 2*NB; blocks [0,NB) -> dst, [NB,2NB) -> src
__global__ __launch_bounds__(256) void reduce_blocks_kernel(
    const int* __restrict__ cnt_d, const int* __restrict__ cnt_s,
    int* __restrict__ bsum) {
  const int arr = blockIdx.x / NB;
  const int blk = blockIdx.x % NB;
  const int* cnt = arr ? cnt_s : cnt_d;
  const int t = threadIdx.x;
  const int base = blk * 1024 + t * 4;
  int s = 0;
  if (base + 3 < NN) {
    const int4 v = *reinterpret_cast<const int4*>(cnt + base);
    s = v.x + v.y + v.z + v.w;
  } else {
#pragma unroll
    for (int i = 0; i < 4; ++i)
      if (base + i < NN) s += cnt[base + i];
  }
  __shared__ int lds[256];
  lds[t] = s;
  __syncthreads();
  for (int d = 128; d > 0; d >>= 1) {
    if (t < d) lds[t] += lds[t + d];
    __syncthreads();
  }
  if (t == 0) bsum[blockIdx.x] = lds[0];
}

// phase 2: one small block scans all 2*NB block sums (segmented by array),
// rewrites bsum[] with exclusive per-array offsets, writes off[NN] totals.
__global__ __launch_bounds__(256) void scan_sums_kernel(
    int* __restrict__ bsum, int* __restrict__ off_d, int* __restrict__ off_s) {
  __shared__ int lds[256];
  const int t = threadIdx.x;
  const int v = (t < 2 * NB) ? bsum[t] : 0;
  lds[t] = v;
  __syncthreads();
  int acc = v;
  for (int d = 1; d < 256; d <<= 1) {
    const int add = (t >= d) ? lds[t - d] : 0;
    __syncthreads();
    acc += add;
    lds[t] = acc;
    __syncthreads();
  }
  // lds[t] now inclusive scan over the combined array
  const int total_d = lds[NB - 1];
  const int excl = acc - v;
  if (t < NB) bsum[t] = excl;
  else if (t < 2 * NB) bsum[t] = excl - total_d;
  if (t == 0) {
    off_d[NN] = total_d;
    off_s[NN] = lds[2 * NB - 1] - total_d;
  }
}

// phase 3: per-block exclusive scan + block offset; writes off[] and cursor.
__global__ __launch_bounds__(256) void scan_apply_kernel(
    int* __restrict__ cnt_d, int* __restrict__ off_d, int* __restrict__ cnt_s,
    int* __restrict__ off_s, const int* __restrict__ bsum) {
  const int arr = blockIdx.x / NB;
  const int blk = blockIdx.x % NB;
  int* cnt = arr ? cnt_s : cnt_d;
  int* off = arr ? off_s : off_d;
  const int t = threadIdx.x;
  const int base = blk * 1024 + t * 4;
  int4 v = make_int4(0, 0, 0, 0);
  const bool full = (base + 3 < NN);
  if (full) {
    v = *reinterpret_cast<const int4*>(cnt + base);
  } else {
    int tmp[4] = {0, 0, 0, 0};
#pragma unroll
    for (int i = 0; i < 4; ++i)
      if (base + i < NN) tmp[i] = cnt[base + i];
    v = make_int4(tmp[0], tmp[1], tmp[2], tmp[3]);
  }
  const int s = v.x + v.y + v.z + v.w;
  __shared__ int lds[256];
  lds[t] = s;
  __syncthreads();
  int acc = s;
  for (int d = 1; d < 256; d <<= 1) {
    const int add = (t >= d) ? lds[t - d] : 0;
    __syncthreads();
    acc += add;
    lds[t] = acc;
    __syncthreads();
  }
  const int pre = bsum[blockIdx.x] + acc - s;
  const int o0 = pre, o1 = o0 + v.x, o2 = o1 + v.y, o3 = o2 + v.z;
  if (full) {
    *reinterpret_cast<int4*>(off + base) = make_int4(o0, o1, o2, o3);
    *reinterpret_cast<int4*>(cnt + base) = make_int4(o0, o1, o2, o3);
  } else {
    const int oo[4] = {o0, o1, o2, o3};
#pragma unroll
    for (int i = 0; i < 4; ++i)
      if (base + i < NN) {
        off[base + i] = oo[i];
        cnt[base + i] = oo[i];
      }
  }
}

__global__ __launch_bounds__(256) void scatter_kernel(
    const int* __restrict__ ei, int* __restrict__ cur_dst,
    int* __restrict__ cur_src, int2* __restrict__ lst_dst,
    int2* __restrict__ lst_src) {
  const int e = blockIdx.x * 256 + threadIdx.x;
  if (e >= NE) return;
  const int s = ei[e], d = ei[NE + e];
  const int p = atomicAdd(&cur_dst[d], 1);
  lst_dst[p] = make_int2(e, s);
  const int q = atomicAdd(&cur_src[s], 1);
  lst_src[q] = make_int2(e, d);
}

// ---------------- gather: agg[n] = sum_e relu(x[partner] + ea[e]) ----------
// 16 lanes per node (float4 each), 16 nodes per 256-thread block.
__global__ __launch_bounds__(256) void gather_kernel(
    const float* __restrict__ x, const float* __restrict__ ea,
    const int* __restrict__ off, const int2* __restrict__ lst,
    float* __restrict__ agg) {
  const int t = threadIdx.x;
  const int n = blockIdx.x * 16 + (t >> 4);
  const int c = (t & 15) * 4;
  if (n >= NN) return;
  const int beg = off[n];
  const int end = off[n + 1];
  float4 acc = make_float4(0.f, 0.f, 0.f, 0.f);
  for (int k = beg; k < end; ++k) {
    const int2 p = lst[k];
    const float4 a = *reinterpret_cast<const float4*>(ea + (size_t)p.x * DD + c);
    const float4 xv = *reinterpret_cast<const float4*>(x + (size_t)p.y * DD + c);
    acc.x += fmaxf(a.x + xv.x, 0.f);
    acc.y += fmaxf(a.y + xv.y, 0.f);
    acc.z += fmaxf(a.z + xv.z, 0.f);
    acc.w += fmaxf(a.w + xv.w, 0.f);
  }
  *reinterpret_cast<float4*>(agg + (size_t)n * DD + c) = acc;
}

// ---------------- fallback edge pass (atomic) if ws too small -------------
__global__ __launch_bounds__(256) void edge_kernel(
    const float* __restrict__ x, const int* __restrict__ ei,
    const float* __restrict__ ea, float* __restrict__ agg_in,
    float* __restrict__ agg_out) {
  const int tid = blockIdx.x * 256 + threadIdx.x;
  const int e = tid >> 4;
  if (e >= NE) return;
  const int c = (tid & 15) * 4;
  const int s = ei[e];
  const int d = ei[NE + e];
  const float4 a = *reinterpret_cast<const float4*>(ea + (size_t)e * DD + c);
  const float4 xs = *reinterpret_cast<const float4*>(x + (size_t)s * DD + c);
  const float4 xd = *reinterpret_cast<const float4*>(x + (size_t)d * DD + c);
  float* pi = agg_in + (size_t)d * DD + c;
  unsafeAtomicAdd(pi + 0, fmaxf(xs.x + a.x, 0.f));
  unsafeAtomicAdd(pi + 1, fmaxf(xs.y + a.y, 0.f));
  unsafeAtomicAdd(pi + 2, fmaxf(xs.z + a.z, 0.f));
  unsafeAtomicAdd(pi + 3, fmaxf(xs.w + a.w, 0.f));
  float* po = agg_out + (size_t)s * DD + c;
  unsafeAtomicAdd(po + 0, fmaxf(xd.x + a.x, 0.f));
  unsafeAtomicAdd(po + 1, fmaxf(xd.y + a.y, 0.f));
  unsafeAtomicAdd(po + 2, fmaxf(xd.z + a.z, 0.f));
  unsafeAtomicAdd(po + 3, fmaxf(xd.w + a.w, 0.f));
}

// ---------------- fused node MLP + final projection ----------------
#define LDSTRIDE 66

#define LOAD_TILE(SRC, Bbuf)                                                  \
  {                                                                           \
    const int r = t >> 2;                                                     \
    const int cb = (t & 3) * 16;                                              \
    const int n = n0 + r;                                                     \
    _Pragma("unroll") for (int ii = 0; ii < 4; ++ii) {                        \
      float4 v = make_float4(0.f, 0.f, 0.f, 0.f);                             \
      if (n < NN)                                                             \
        v = *reinterpret_cast<const float4*>((SRC) + (size_t)n * DD + cb +    \
                                             ii * 4);                         \
      const int cc = cb + ii * 4;                                             \
      Bbuf[(cc + 0) * LDSTRIDE + r] = v.x;                                    \
      Bbuf[(cc + 1) * LDSTRIDE + r] = v.y;                                    \
      Bbuf[(cc + 2) * LDSTRIDE + r] = v.z;                                    \
      Bbuf[(cc + 3) * LDSTRIDE + r] = v.w;                                    \
    }                                                                         \
  }

#define MM_PASS(Bbuf, Wmat, ACC)                                              \
  {                                                                           \
    _Pragma("unroll 8") for (int k = 0; k < 64; ++k) {                        \
      const float4 w =                                                        \
          *reinterpret_cast<const float4*>((Wmat) + k * 64 + jq * 4);         \
      _Pragma("unroll") for (int ii = 0; ii < 4; ++ii) {                      \
        const float aa = Bbuf[k * LDSTRIDE + nq * 4 + ii];                    \
        ACC[ii][0] = fmaf(aa, w.x, ACC[ii][0]);                               \
        ACC[ii][1] = fmaf(aa, w.y, ACC[ii][1]);                               \
        ACC[ii][2] = fmaf(aa, w.z, ACC[ii][2]);                               \
        ACC[ii][3] = fmaf(aa, w.w, ACC[ii][3]);                               \
      }                                                                       \
    }                                                                         \
  }

#define STORE_H(Bbuf, ACC, BV)                                                \
  {                                                                           \
    _Pragma("unroll") for (int ii = 0; ii < 4; ++ii) {                        \
      Bbuf[(jq * 4 + 0) * LDSTRIDE + nq * 4 + ii] =                           \
          fmaxf(ACC[ii][0] + BV.x, 0.f);                                      \
      Bbuf[(jq * 4 + 1) * LDSTRIDE + nq * 4 + ii] =                           \
          fmaxf(ACC[ii][1] + BV.y, 0.f);                                      \
      Bbuf[(jq * 4 + 2) * LDSTRIDE + nq * 4 + ii] =                           \
          fmaxf(ACC[ii][2] + BV.z, 0.f);                                      \
      Bbuf[(jq * 4 + 3) * LDSTRIDE + nq * 4 + ii] =                           \
          fmaxf(ACC[ii][3] + BV.w, 0.f);                                      \
    }                                                                         \
  }

__global__ __launch_bounds__(256) void node_kernel(
    const float* __restrict__ x, const float* __restrict__ agg_in,
    const float* __restrict__ agg_out, const float* __restrict__ W1,
    const float* __restrict__ b1, const float* __restrict__ Wc1,
    const float* __restrict__ Wc2, const float* __restrict__ bc,
    const float* __restrict__ Wl0, float* __restrict__ out) {
  __shared__ float B0[64 * LDSTRIDE];
  __shared__ float B1[64 * LDSTRIDE];
  const int t = threadIdx.x;
  const int n0 = blockIdx.x * 64;
  const int jq = t & 15;
  const int nq = t >> 4;

  const float4 b1v = *reinterpret_cast<const float4*>(b1 + jq * 4);
  const float4 bcv = *reinterpret_cast<const float4*>(bc + jq * 4);

  float oacc[4][4];
#pragma unroll
  for (int ii = 0; ii < 4; ++ii)
#pragma unroll
    for (int jj = 0; jj < 4; ++jj) oacc[ii][jj] = 0.f;

  LOAD_TILE(agg_in, B0);
  __syncthreads();
  {
    float acc[4][4] = {};
    MM_PASS(B0, W1, acc);
    STORE_H(B1, acc, b1v);
  }
  __syncthreads();
  MM_PASS(B1, Wc1, oacc);
  LOAD_TILE(agg_out, B0);
  __syncthreads();
  {
    float acc[4][4] = {};
    MM_PASS(B0, W1, acc);
    STORE_H(B1, acc, b1v);
  }
  __syncthreads();
  MM_PASS(B1, Wc2, oacc);
  LOAD_TILE(x, B0);
  __syncthreads();
  MM_PASS(B0, Wl0, oacc);

#pragma unroll
  for (int ii = 0; ii < 4; ++ii) {
    const int n = n0 + nq * 4 + ii;
    if (n < NN) {
      float4 v;
      v.x = oacc[ii][0] + bcv.x;
      v.y = oacc[ii][1] + bcv.y;
      v.z = oacc[ii][2] + bcv.z;
      v.w = oacc[ii][3] + bcv.w;
      *reinterpret_cast<float4*>(out + (size_t)n * DD + jq * 4) = v;
    }
  }
}

extern "C" void kernel_launch(void* const* d_in, const int* in_sizes, int n_in,
                              void* d_out, int out_size, void* d_ws,
                              size_t ws_size, hipStream_t stream) {
  const float* x = (const float*)d_in[0];
  const int* ei = (const int*)d_in[1];
  const float* ea = (const float*)d_in[2];
  const float* W1 = (const float*)d_in[3];
  const float* b1 = (const float*)d_in[4];
  const float* W2 = (const float*)d_in[5];
  const float* b2 = (const float*)d_in[6];
  const float* Wl = (const float*)d_in[7];
  const float* bl = (const float*)d_in[8];
  float* out = (float*)d_out;
  float* ws = (float*)d_ws;

  // shared layout head: agg buffers
  float* agg_in = ws;
  float* agg_out = agg_in + (size_t)NN * DD;

  // CSR-path layout (keep 16B alignment at every boundary)
  int2* lst_dst = (int2*)(agg_out + (size_t)NN * DD);
  int2* lst_src = lst_dst + NE;
  int* cur_dst = (int*)(lst_src + NE);
  int* cur_src = cur_dst + NN;
  int* off_dst = cur_src + NN;       // NN+4 ints
  int* off_src = off_dst + NN + 4;   // NN+4 ints
  int* bsum = off_src + NN + 4;      // 2*NB (+pad) ints
  float* Wc1 = (float*)(bsum + 256);
  float* Wc2 = Wc1 + 4096;
  float* bc = Wc2 + 4096;
  const size_t need = (size_t)((char*)(bc + 64) - (char*)ws);  // ~72.8 MB

  const bool csr_ok = ws_size >= need;
  if (!csr_ok) {
    // fallback layout (old atomic path)
    Wc1 = agg_out + (size_t)NN * DD;
    Wc2 = Wc1 + 4096;
    bc = Wc2 + 4096;
  }

  precompute_kernel<<<32, 256, 0, stream>>>(W2, b2, Wl, bl, Wc1, Wc2, bc);

  if (csr_ok) {
    hipMemsetAsync(cur_dst, 0, 2 * (size_t)NN * sizeof(int), stream);
    hist_kernel<<<(NE + 255) / 256, 256, 0, stream>>>(ei, cur_dst, cur_src);
    reduce_blocks_kernel<<<2 * NB, 256, 0, stream>>>(cur_dst, cur_src, bsum);
    scan_sums_kernel<<<1, 256, 0, stream>>>(bsum, off_dst, off_src);
    scan_apply_kernel<<<2 * NB, 256, 0, stream>>>(cur_dst, off_dst, cur_src,
                                                  off_src, bsum);
    scatter_kernel<<<(NE + 255) / 256, 256, 0, stream>>>(ei, cur_dst, cur_src,
                                                         lst_dst, lst_src);
    gather_kernel<<<(NN + 15) / 16, 256, 0, stream>>>(x, ea, off_dst, lst_dst,
                                                      agg_in);
    gather_kernel<<<(NN + 15) / 16, 256, 0, stream>>>(x, ea, off_src, lst_src,
                                                      agg_out);
  } else {
    hipMemsetAsync(agg_in, 0, 2 * (size_t)NN * DD * sizeof(float), stream);
    edge_kernel<<<((size_t)NE * 16 + 255) / 256, 256, 0, stream>>>(
        x, ei, ea, agg_in, agg_out);
  }

  node_kernel<<<(NN + 63) / 64, 256, 0, stream>>>(
      x, agg_in, agg_out, W1, b1, Wc1, Wc2, bc, Wl /* rows 0..63 */, out);
}